// Round 14
// baseline (199.380 us; speedup 1.0000x reference)
//
#include <hip/hip_runtime.h>

// 3x3 conv (sparse weights treated dense), NCHW/OIHW, stride1 pad1, fp32 I/O.
// B=32, CIN=COUT=256, H=W=56.
//
// R14 = R12 + 3-tap phases. R13 taught: occupancy is REGISTER-capped at
// 2 waves/SIMD for m4n7 (112 AGPR + ~128 VGPR = 240 of 512) — LDS diet was
// pointless. So cut per-wave sync overhead instead: phase = (cb, kh row),
// taps kw=0..2 in one straight-line region -> 84 MFMA per barrier-pair
// (3x R12), compiler pipelines tap kw+1's ds_reads under tap kw's MFMAs.
// Barriers/block 144 -> 48.
//  - A staged per-phase as 3 slabs (24KB), dbuf; X dbuf (R12 scheme).
//    LDS = 2x24 + 2x16 = 80KB -> 2 blocks/CU.
//  - FIFO vmcnt ledger: q0/q1 -> vmcnt(12), q2 -> vmcnt(16); never 0
//    mid-loop; cb7 stages dummies (dead targets) to keep counts uniform.
//  - swizzle, m4n7 shape, epilogue: R12 verbatim (proven 126.5us + 4x
//    conflict cut).

typedef __attribute__((ext_vector_type(8))) short short8;
typedef __attribute__((ext_vector_type(4))) float f32x4;
typedef __attribute__((ext_vector_type(4))) int i32x4;

constexpr int BB = 32, CIN = 256, COUT = 256, H = 56, W = 56, HW = H * W;
constexpr int HP = 58, WP = 58;

constexpr size_t XP_ELEMS = (size_t)BB * HP * WP * CIN;
constexpr size_t WB_ELEMS = (size_t)COUT * 9 * CIN;
constexpr size_t WS_NEEDED = (XP_ELEMS + WB_ELEMS) * 2;

__device__ __forceinline__ ushort f2bf(float f) {
    unsigned x = __float_as_uint(f);
    unsigned r = (x + 0x7FFFu + ((x >> 16) & 1u)) >> 16;   // RNE
    return (ushort)r;
}

// ---------------- prep kernels (unchanged) ----------------

__global__ __launch_bounds__(256)
void prep_xp(const float* __restrict__ x, ushort* __restrict__ xp) {
    const int bi = blockIdx.x;            // b*58 + padded row i
    const int b = bi / HP, i = bi % HP;
    ushort* dst = xp + (size_t)bi * WP * CIN;
    const int tid = threadIdx.x;

    if (i == 0 || i == HP - 1) {
        i32x4 z = {0, 0, 0, 0};
        for (int k = tid; k < WP * CIN / 8; k += 256) ((i32x4*)dst)[k] = z;
        return;
    }

    __shared__ ushort t[W][CIN + 2];
    const int lane = tid & 63, wv = tid >> 6;
    if (lane < W) {
        const float* src = x + (size_t)b * CIN * HW + (size_t)(i - 1) * W + lane;
        for (int cin = wv; cin < CIN; cin += 4)
            t[lane][cin] = f2bf(src[(size_t)cin * HW]);
    }
    __syncthreads();
    for (int c = 0; c < WP; ++c)
        dst[c * CIN + tid] = (c == 0 || c == WP - 1) ? (ushort)0 : t[c - 1][tid];
}

// wb2: [t = cb*9+tap][cout][ci], ci = cin%32. Slab = 8192 elems.
__global__ __launch_bounds__(256)
void prep_wb2(const float* __restrict__ w, ushort* __restrict__ wb2) {
    const int d = blockIdx.x * 256 + threadIdx.x;
    const int ci = d & 31;
    const int cout = (d >> 5) & 255;
    const int r = d >> 13;                // 0..71
    const int tap = r % 9, cb = r / 9;
    const int cin = cb * 32 + ci;
    wb2[d] = f2bf(w[((size_t)cout * CIN + cin) * 9 + tap]);
}

// ---------------- MFMA conv ----------------

#define SCHED_FENCE() __builtin_amdgcn_sched_barrier(0)
#define WAITV0  asm volatile("s_waitcnt vmcnt(0)"  ::: "memory")
#define WAITV12 asm volatile("s_waitcnt vmcnt(12)" ::: "memory")
#define WAITV16 asm volatile("s_waitcnt vmcnt(16)" ::: "memory")

__device__ __forceinline__ void gload_lds16(const ushort* g, ushort* l) {
    __builtin_amdgcn_global_load_lds(
        (const __attribute__((address_space(1))) void*)g,
        (__attribute__((address_space(3))) void*)l, 16, 0, 0);
}

// 16B-chunk involution: mixes bits 3-5 into 0-2; self-inverse; bits>=6 fixed.
__device__ __forceinline__ int swz(int c) { return c ^ ((c >> 3) & 7); }

__global__ __launch_bounds__(256, 2)
void conv_mfma(const ushort* __restrict__ xp, const ushort* __restrict__ wb2,
               float* __restrict__ out) {
    // XCD-aware swizzle: 896 blocks = 8 * 112
    int bx = blockIdx.x;
    bx = (bx & 7) * 112 + (bx >> 3);

    const int b  = bx / 28;
    const int p0 = (bx % 28) * 112;        // 112-pix strip = 2 output rows
    const int r0 = p0 / 56;                // first padded input row

    const int tid  = threadIdx.x;
    const int wv   = tid >> 6;             // 0..3, wave -> couts [64wv, 64wv+64)
    const int lane = tid & 63;
    const int ml   = lane & 15;
    const int g    = lane >> 4;

    __shared__ ushort As0[3 * 8192], As1[3 * 8192];  // 2 x 24KB (3 slabs each)
    __shared__ ushort Xs0[8192], Xs1[8192];          // 2 x 16KB

    // A-frag read byte offsets within a slab (swizzled, constant per thread)
    int aoffB[4];
    #pragma unroll
    for (int mi = 0; mi < 4; ++mi)
        aoffB[mi] = swz((64 * wv + 16 * mi + ml) * 4 + g) * 16;
    // B-frag chunk bases: pixel p_ = p0+16nf+ml -> slot*4 + g
    int cbase[7];
    #pragma unroll
    for (int nf = 0; nf < 7; ++nf) {
        const int p_  = p0 + 16 * nf + ml;
        const int hl  = (p_ >= p0 + 56) ? 1 : 0;
        const int col = p_ - 56 * (r0 + hl);
        cbase[nf] = (hl * 58 + col) * 4 + g;
    }
    // staging source offsets: position q = k*256+tid holds logical chunk swz(q)
    int goffA[4], goffX[4];
    #pragma unroll
    for (int k = 0; k < 4; ++k) {
        const int q = k * 256 + tid;
        const int c = swz(q);
        goffA[k] = (c >> 2) * 32 + (c & 3) * 8;                   // slab elems
        goffX[k] = (c < 928) ? ((c >> 2) * 256 + (c & 3) * 8) : 0;
    }
    const size_t xbase = ((size_t)b * HP + r0) * WP * CIN;

    f32x4 acc[4][7] = {};

    // stage one 3-slab A group for phase PH into BUF (12 gloads/thread)
    #define STAGE_A3(PH, BUF)                                                   \
        { int _s0 = (PH) * 3; if (_s0 >= 72) _s0 -= 72;                         \
          _Pragma("unroll")                                                     \
          for (int s = 0; s < 3; ++s) {                                         \
              const ushort* _src = wb2 + (size_t)(_s0 + s) * 8192;              \
              _Pragma("unroll")                                                 \
              for (int k = 0; k < 4; ++k)                                       \
                  gload_lds16(_src + goffA[k],                                  \
                              (BUF) + s * 8192 + (k * 256 + wv * 64) * 8);      \
          } }
    #define STAGE_X(CB, BUF)                                                    \
        { const ushort* _s = xp + xbase + (CB) * 32;                            \
          _Pragma("unroll")                                                     \
          for (int k = 0; k < 4; ++k)                                           \
              gload_lds16(_s + goffX[k], (BUF) + (k * 256 + wv * 64) * 8); }

    // prologue: X(0), A3(0)->As0, A3(1)->As1; full drain; sync
    STAGE_X(0, Xs0);
    STAGE_A3(0, As0);
    STAGE_A3(1, As1);
    WAITV0;
    __syncthreads();

    for (int cb = 0; cb < 8; ++cb) {
        #pragma unroll
        for (int q = 0; q < 3; ++q) {      // phase = kernel row kh = q
            const int ph = cb * 3 + q;

            // head: retire A3(ph) (+X(cb) at q0), FIFO-derived counts
            if (q == 2) { WAITV16; } else { WAITV12; }
            SCHED_FENCE();
            __builtin_amdgcn_s_barrier();
            SCHED_FENCE();

            const ushort* Ab = (ph & 1) ? As1 : As0;
            const ushort* Xb = (cb & 1) ? Xs1 : Xs0;

            // 3 taps (kw = 0..2) straight-line; compiler pipelines reads
            #pragma unroll
            for (int kw = 0; kw < 3; ++kw) {
                short8 av[4], bv[7];
                #pragma unroll
                for (int mi = 0; mi < 4; ++mi)
                    av[mi] = *(const short8*)((const char*)Ab + kw * 16384 + aoffB[mi]);
                #pragma unroll
                for (int nf = 0; nf < 7; ++nf) {
                    const int c = cbase[nf] + 4 * (q * 58 + kw);
                    bv[nf] = *(const short8*)((const char*)Xb + swz(c) * 16);
                }
                __builtin_amdgcn_s_setprio(1);
                #pragma unroll
                for (int mi = 0; mi < 4; ++mi)
                    #pragma unroll
                    for (int nf = 0; nf < 7; ++nf)
                        acc[mi][nf] = __builtin_amdgcn_mfma_f32_16x16x32_bf16(
                                          av[mi], bv[nf], acc[mi][nf], 0, 0, 0);
                __builtin_amdgcn_s_setprio(0);
            }
            SCHED_FENCE();
            __builtin_amdgcn_s_barrier();  // all waves done reading
            SCHED_FENCE();

            // tail: stage A3(ph+2) into the buffer just read; X at q1
            {
                int phn = ph + 2;
                if (phn >= 24) phn -= 24;  // dummy at end (dead target)
                ushort* abuf = (ph & 1) ? As1 : As0;
                STAGE_A3(phn, abuf);
            }
            if (q == 1) {
                const int cbn = (cb < 7) ? cb + 1 : 0;  // cb7: dummy
                STAGE_X(cbn, (cb & 1) ? Xs0 : Xs1);
            }
            SCHED_FENCE();
        }
    }
    WAITV0;                                // drain tail dummy stages

    // epilogue: D[row=4g+r][col=ml] (verified R2-R13)
    float* ob = out + (size_t)b * COUT * HW;
    #pragma unroll
    for (int mi = 0; mi < 4; ++mi)
        #pragma unroll
        for (int nf = 0; nf < 7; ++nf)
            #pragma unroll
            for (int r = 0; r < 4; ++r) {
                const int cout_l = 64 * wv + 16 * mi + 4 * g + r;
                const int p_ = p0 + 16 * nf + ml;
                ob[(size_t)cout_l * HW + p_] = acc[mi][nf][r];
            }
    #undef STAGE_A3
    #undef STAGE_X
}

// ---------------- R1 fallback (fp32 sparse direct) ----------------

constexpr int WSZ = CIN * 9;
constexpr int NIN = 54 * 54;

__global__ __launch_bounds__(256)
void sparse_conv3x3(const float* __restrict__ x,
                    const float* __restrict__ wgt,
                    float* __restrict__ out) {
    const int bc = blockIdx.x, cout = bc % COUT, b = bc / COUT;
    const int tid = threadIdx.x;
    __shared__ int2 s_ent[WSZ];
    __shared__ unsigned char s_kk[WSZ];
    __shared__ int s_cnt[257];
    const float* wc = wgt + (size_t)cout * WSZ;
    float mv[9]; int cnt = 0;
    #pragma unroll
    for (int i = 0; i < 9; ++i) { mv[i] = wc[tid * 9 + i]; if (mv[i] != 0.0f) cnt++; }
    s_cnt[tid] = cnt; __syncthreads();
    if (tid == 0) { int run = 0; for (int t = 0; t < 256; ++t) { int c = s_cnt[t]; s_cnt[t] = run; run += c; } s_cnt[256] = run; }
    __syncthreads();
    { int pos = s_cnt[tid];
      #pragma unroll
      for (int i = 0; i < 9; ++i) if (mv[i] != 0.0f) {
          const int kh = i / 3, kw = i - kh * 3;
          int2 e; e.x = (tid * HW + (kh - 1) * W + (kw - 1)) * 4; e.y = __float_as_int(mv[i]);
          s_ent[pos] = e; s_kk[pos] = (unsigned char)(kh | (kw << 4)); pos++; } }
    __syncthreads();
    const int nnz = s_cnt[256];
    const char* xb = (const char*)(x + (size_t)b * CIN * HW);
    float* ob = out + (size_t)bc * HW;
    for (int o = tid; o < HW; o += 256) {
        int h, w; bool interior = (o < NIN);
        if (interior) { h = 1 + o / 54; w = 1 + (o - (h - 1) * 54); }
        else { int o2 = o - NIN;
            if (o2 < 56) { h = 0; w = o2; } else if (o2 < 112) { h = 55; w = o2 - 56; }
            else if (o2 < 166) { h = 1 + (o2 - 112); w = 0; } else { h = 1 + (o2 - 166); w = 55; } }
        const char* pb = xb + (size_t)(h * W + w) * 4;
        float acc = 0.0f;
        if (interior) {
            #pragma unroll 4
            for (int e = 0; e < nnz; ++e) { const int2 en = s_ent[e];
                acc = fmaf(__int_as_float(en.y), *(const float*)(pb + en.x), acc); }
        } else {
            const int h1 = h - 1, w1 = w - 1;
            for (int e = 0; e < nnz; ++e) { const int2 en = s_ent[e]; const int kk = s_kk[e];
                const int hh = h1 + (kk & 15), ww = w1 + (kk >> 4);
                if ((unsigned)hh < (unsigned)H && (unsigned)ww < (unsigned)W)
                    acc = fmaf(__int_as_float(en.y), *(const float*)(pb + en.x), acc); } }
        ob[h * W + w] = acc;
    }
}

// ---------------- launch ----------------

extern "C" void kernel_launch(void* const* d_in, const int* in_sizes, int n_in,
                              void* d_out, int out_size, void* d_ws, size_t ws_size,
                              hipStream_t stream) {
    const float* x = (const float*)d_in[0];
    const float* w = (const float*)d_in[1];
    float* out = (float*)d_out;

    if (ws_size >= WS_NEEDED) {
        ushort* xp = (ushort*)d_ws;
        ushort* wbp = xp + XP_ELEMS;
        prep_xp<<<BB * HP, 256, 0, stream>>>(x, xp);
        prep_wb2<<<(int)(WB_ELEMS / 256), 256, 0, stream>>>(w, wbp);
        conv_mfma<<<896, 256, 0, stream>>>(xp, wbp, out);
    } else {
        sparse_conv3x3<<<BB * COUT, 256, 0, stream>>>(x, w, out);
    }
}

// Round 15
// 150.594 us; speedup vs baseline: 1.3240x; 1.3240x over previous
//
#include <hip/hip_runtime.h>

// 3x3 conv (sparse weights treated dense), NCHW/OIHW, stride1 pad1, fp32 I/O.
// B=32, CIN=COUT=256, H=W=56.
//
// R15 = R12 + 2-tap phases, sized to FIT (R14 lesson: slab = 16KB not 8;
// arch VGPR <= 144 with 112 AGPR acc; LDS <= 80KB for 2 blocks/CU).
//  - phases/cb: {t0,t1}{t2,t3}{t4,t5}{t6,t7}{t8} -> 56 MFMA per barrier-pair,
//    barriers 144 -> 80 per block.
//  - A: 2 parity buffers x 2 slabs = 64KB; group G(p+2) staged at p's tail
//    into the just-read buffer (R12 pattern at group granularity).
//  - X: SINGLE 16KB region buffer (4 row-regions x 256 chunks). Split stage:
//    rows01(cb+1) at q2 tail, rows23(cb+1) at q4 tail (row last-readers:
//    row0:q1, row1:q2, rows2/3:q4) -> zero-bubble, no 2nd buffer.
//  - FIFO vmcnt ledger (X issued before A at shared tails), hand-walked:
//    head waits {q0:10, q1:8, q2:8, q3:6, q4:8}; never 0 mid-loop; cb7
//    stages wrap to dead-parity targets; single drain at end.

typedef __attribute__((ext_vector_type(8))) short short8;
typedef __attribute__((ext_vector_type(4))) float f32x4;
typedef __attribute__((ext_vector_type(4))) int i32x4;

constexpr int BB = 32, CIN = 256, COUT = 256, H = 56, W = 56, HW = H * W;
constexpr int HP = 58, WP = 58;

constexpr size_t XP_ELEMS = (size_t)BB * HP * WP * CIN;
constexpr size_t WB_ELEMS = (size_t)COUT * 9 * CIN;
constexpr size_t WS_NEEDED = (XP_ELEMS + WB_ELEMS) * 2;

__device__ __forceinline__ ushort f2bf(float f) {
    unsigned x = __float_as_uint(f);
    unsigned r = (x + 0x7FFFu + ((x >> 16) & 1u)) >> 16;   // RNE
    return (ushort)r;
}

// ---------------- prep kernels (unchanged) ----------------

__global__ __launch_bounds__(256)
void prep_xp(const float* __restrict__ x, ushort* __restrict__ xp) {
    const int bi = blockIdx.x;            // b*58 + padded row i
    const int b = bi / HP, i = bi % HP;
    ushort* dst = xp + (size_t)bi * WP * CIN;
    const int tid = threadIdx.x;

    if (i == 0 || i == HP - 1) {
        i32x4 z = {0, 0, 0, 0};
        for (int k = tid; k < WP * CIN / 8; k += 256) ((i32x4*)dst)[k] = z;
        return;
    }

    __shared__ ushort t[W][CIN + 2];
    const int lane = tid & 63, wv = tid >> 6;
    if (lane < W) {
        const float* src = x + (size_t)b * CIN * HW + (size_t)(i - 1) * W + lane;
        for (int cin = wv; cin < CIN; cin += 4)
            t[lane][cin] = f2bf(src[(size_t)cin * HW]);
    }
    __syncthreads();
    for (int c = 0; c < WP; ++c)
        dst[c * CIN + tid] = (c == 0 || c == WP - 1) ? (ushort)0 : t[c - 1][tid];
}

// wb2: [t = cb*9+tap][cout][ci], ci = cin%32. Slab = 8192 elems = 16KB.
__global__ __launch_bounds__(256)
void prep_wb2(const float* __restrict__ w, ushort* __restrict__ wb2) {
    const int d = blockIdx.x * 256 + threadIdx.x;
    const int ci = d & 31;
    const int cout = (d >> 5) & 255;
    const int r = d >> 13;                // 0..71
    const int tap = r % 9, cb = r / 9;
    const int cin = cb * 32 + ci;
    wb2[d] = f2bf(w[((size_t)cout * CIN + cin) * 9 + tap]);
}

// ---------------- MFMA conv ----------------

#define SCHED_FENCE() __builtin_amdgcn_sched_barrier(0)
#define WAITV(N) asm volatile("s_waitcnt vmcnt(" #N ")" ::: "memory")

__device__ __forceinline__ void gload_lds16(const ushort* g, ushort* l) {
    __builtin_amdgcn_global_load_lds(
        (const __attribute__((address_space(1))) void*)g,
        (__attribute__((address_space(3))) void*)l, 16, 0, 0);
}

// 16B-chunk involution: mixes bits 3-5 into 0-2; self-inverse; bits>=6 fixed.
__device__ __forceinline__ int swz(int c) { return c ^ ((c >> 3) & 7); }

__global__ __launch_bounds__(256, 2)
void conv_mfma(const ushort* __restrict__ xp, const ushort* __restrict__ wb2,
               float* __restrict__ out) {
    // XCD-aware swizzle: 896 blocks = 8 * 112
    int bx = blockIdx.x;
    bx = (bx & 7) * 112 + (bx >> 3);

    const int b  = bx / 28;
    const int p0 = (bx % 28) * 112;        // 112-pix strip = 2 output rows
    const int r0 = p0 / 56;                // first padded input row

    const int tid  = threadIdx.x;
    const int wv   = tid >> 6;             // 0..3, wave -> couts [64wv, 64wv+64)
    const int lane = tid & 63;
    const int ml   = lane & 15;
    const int g    = lane >> 4;

    __shared__ ushort As0[2 * 8192], As1[2 * 8192];  // 2 bufs x 2 slabs = 64KB
    __shared__ ushort Xs[4 * 2048];                  // 16KB: 4 row-regions x 256 chunks

    // A-frag read byte offsets within a slab (swizzled, constant per thread)
    int aoffB[4];
    #pragma unroll
    for (int mi = 0; mi < 4; ++mi)
        aoffB[mi] = swz((64 * wv + 16 * mi + ml) * 4 + g) * 16;
    // B-frag chunk bases: pixel p_ = p0+16nf+ml -> region hl*256 + col*4 + g
    int cbase[7];
    #pragma unroll
    for (int nf = 0; nf < 7; ++nf) {
        const int p_  = p0 + 16 * nf + ml;
        const int hl  = (p_ >= p0 + 56) ? 1 : 0;
        const int col = p_ - 56 * (r0 + hl);
        cbase[nf] = hl * 256 + col * 4 + g;
    }
    // A staging source offsets: position q = k*256+tid holds chunk swz(q)
    int goffA[4];
    #pragma unroll
    for (int k = 0; k < 4; ++k) {
        const int c = swz(k * 256 + tid);
        goffA[k] = (c >> 2) * 32 + (c & 3) * 8;                 // slab elems
    }
    // X row staging: position (rr*256+tid) holds chunk rr*256+ii (R13, proven)
    int xoff;
    {
        const int ii = (tid & 0xC0) | ((tid & 63) ^ (((tid & 63) >> 3) & 7));
        xoff = (ii < 232) ? ((ii >> 2) * CIN + (ii & 3) * 8) : 0;
    }
    const size_t xbase = ((size_t)b * HP + r0) * WP * CIN;

    f32x4 acc[4][7] = {};

    // stage a 2-slab A group starting at slab S (wraps at 72) into BUF
    #define STAGE_A2(S, BUF)                                                    \
        { _Pragma("unroll")                                                     \
          for (int s = 0; s < 2; ++s) {                                         \
              int _sl = (S) + s; if (_sl >= 72) _sl -= 72;                      \
              const ushort* _src = wb2 + (size_t)_sl * 8192;                    \
              _Pragma("unroll")                                                 \
              for (int k = 0; k < 4; ++k)                                       \
                  gload_lds16(_src + goffA[k],                                  \
                              (BUF) + s * 8192 + (k * 256 + wv * 64) * 8);      \
          } }
    #define STAGE_A1(S, BUF)                                                    \
        { int _sl = (S); if (_sl >= 72) _sl -= 72;                              \
          const ushort* _src = wb2 + (size_t)_sl * 8192;                        \
          _Pragma("unroll")                                                     \
          for (int k = 0; k < 4; ++k)                                           \
              gload_lds16(_src + goffA[k], (BUF) + (k * 256 + wv * 64) * 8); }
    // stage X rows RR, RR+1 of cin-block CBN (2 gloads/thread)
    #define STAGE_XPAIR(RR, CBN)                                                \
        { _Pragma("unroll")                                                     \
          for (int r_ = 0; r_ < 2; ++r_)                                        \
              gload_lds16(xp + xbase + (size_t)((RR) + r_) * WP * CIN           \
                              + (CBN) * 32 + xoff,                              \
                          &Xs[(((RR) + r_) * 256 + wv * 64) * 8]); }

    // prologue: X rows0-3(cb0), G(p0)={t0,t1}->buf0, G(p1)={t2,t3}->buf1
    STAGE_XPAIR(0, 0);
    STAGE_XPAIR(2, 0);
    STAGE_A2(0, As0);
    STAGE_A2(2, As1);
    WAITV(0);
    __syncthreads();

    // phase q taps: q<4 -> {2q, 2q+1}; q4 -> {8}. buffer parity = (cb+q)&1.
    #define PHASE(CB, Q, NTAPS, HWAIT)                                          \
        {                                                                       \
            WAITV(HWAIT);                                                       \
            SCHED_FENCE();                                                      \
            __builtin_amdgcn_s_barrier();                                       \
            SCHED_FENCE();                                                      \
            const ushort* Ab = (((CB) + (Q)) & 1) ? As1 : As0;                  \
            _Pragma("unroll")                                                   \
            for (int tp = 0; tp < (NTAPS); ++tp) {                              \
                const int tap = 2 * (Q) + tp;                                   \
                const int kh = tap / 3, kw = tap - kh * 3;                      \
                short8 av[4], bv[7];                                            \
                _Pragma("unroll")                                               \
                for (int mi = 0; mi < 4; ++mi)                                  \
                    av[mi] = *(const short8*)((const char*)Ab + tp * 16384      \
                                              + aoffB[mi]);                     \
                _Pragma("unroll")                                               \
                for (int nf = 0; nf < 7; ++nf) {                                \
                    const int c = cbase[nf] + kh * 256 + kw * 4;                \
                    bv[nf] = *(const short8*)((const char*)Xs + swz(c) * 16);   \
                }                                                               \
                __builtin_amdgcn_s_setprio(1);                                  \
                _Pragma("unroll")                                               \
                for (int mi = 0; mi < 4; ++mi)                                  \
                    _Pragma("unroll")                                           \
                    for (int nf = 0; nf < 7; ++nf)                              \
                        acc[mi][nf] = __builtin_amdgcn_mfma_f32_16x16x32_bf16(  \
                                          av[mi], bv[nf], acc[mi][nf], 0, 0, 0);\
                __builtin_amdgcn_s_setprio(0);                                  \
            }                                                                   \
            SCHED_FENCE();                                                      \
            __builtin_amdgcn_s_barrier();                                       \
            SCHED_FENCE();                                                      \
        }

    for (int cbp = 0; cbp < 4; ++cbp) {
        #pragma unroll
        for (int hf = 0; hf < 2; ++hf) {
            const int cb  = 2 * cbp + hf;
            const int t0  = 9 * cb;
            const int cbn = (cb < 7) ? cb + 1 : 0;  // cb7: dummy (dead/drained)
            ushort* bufE = ((cb & 1) == 0) ? As0 : As1;  // parity (cb+q)&1 == 0
            ushort* bufO = ((cb & 1) == 0) ? As1 : As0;

            // q0: reads bufE; tail stages G(q2) into bufE
            PHASE(cb, 0, 2, 10);
            STAGE_A2(t0 + 4, bufE);
            SCHED_FENCE();
            // q1: reads bufO; tail stages G(q3) into bufO
            PHASE(cb, 1, 2, 8);
            STAGE_A2(t0 + 6, bufO);
            SCHED_FENCE();
            // q2: reads bufE; tail: X rows01(cb+1) FIRST, then G(q4) into bufE
            PHASE(cb, 2, 2, 8);
            STAGE_XPAIR(0, cbn);
            STAGE_A1(t0 + 8, bufE);
            SCHED_FENCE();
            // q3: reads bufO; tail stages G(next q0) into bufO
            PHASE(cb, 3, 2, 6);
            STAGE_A2(t0 + 9, bufO);
            SCHED_FENCE();
            // q4 (tap 8): reads bufE; tail: X rows23(cb+1), then G(next q1) into bufE
            PHASE(cb, 4, 1, 8);
            STAGE_XPAIR(2, cbn);
            STAGE_A2(t0 + 11, bufE);
            SCHED_FENCE();
        }
    }
    WAITV(0);                              // drain tail dummy stages

    // epilogue: D[row=4g+r][col=ml] (verified R2-R14)
    float* ob = out + (size_t)b * COUT * HW;
    #pragma unroll
    for (int mi = 0; mi < 4; ++mi)
        #pragma unroll
        for (int nf = 0; nf < 7; ++nf)
            #pragma unroll
            for (int r = 0; r < 4; ++r) {
                const int cout_l = 64 * wv + 16 * mi + 4 * g + r;
                const int p_ = p0 + 16 * nf + ml;
                ob[(size_t)cout_l * HW + p_] = acc[mi][nf][r];
            }
    #undef STAGE_A2
    #undef STAGE_A1
    #undef STAGE_XPAIR
    #undef PHASE
}

// ---------------- R1 fallback (fp32 sparse direct) ----------------

constexpr int WSZ = CIN * 9;
constexpr int NIN = 54 * 54;

__global__ __launch_bounds__(256)
void sparse_conv3x3(const float* __restrict__ x,
                    const float* __restrict__ wgt,
                    float* __restrict__ out) {
    const int bc = blockIdx.x, cout = bc % COUT, b = bc / COUT;
    const int tid = threadIdx.x;
    __shared__ int2 s_ent[WSZ];
    __shared__ unsigned char s_kk[WSZ];
    __shared__ int s_cnt[257];
    const float* wc = wgt + (size_t)cout * WSZ;
    float mv[9]; int cnt = 0;
    #pragma unroll
    for (int i = 0; i < 9; ++i) { mv[i] = wc[tid * 9 + i]; if (mv[i] != 0.0f) cnt++; }
    s_cnt[tid] = cnt; __syncthreads();
    if (tid == 0) { int run = 0; for (int t = 0; t < 256; ++t) { int c = s_cnt[t]; s_cnt[t] = run; run += c; } s_cnt[256] = run; }
    __syncthreads();
    { int pos = s_cnt[tid];
      #pragma unroll
      for (int i = 0; i < 9; ++i) if (mv[i] != 0.0f) {
          const int kh = i / 3, kw = i - kh * 3;
          int2 e; e.x = (tid * HW + (kh - 1) * W + (kw - 1)) * 4; e.y = __float_as_int(mv[i]);
          s_ent[pos] = e; s_kk[pos] = (unsigned char)(kh | (kw << 4)); pos++; } }
    __syncthreads();
    const int nnz = s_cnt[256];
    const char* xb = (const char*)(x + (size_t)b * CIN * HW);
    float* ob = out + (size_t)bc * HW;
    for (int o = tid; o < HW; o += 256) {
        int h, w; bool interior = (o < NIN);
        if (interior) { h = 1 + o / 54; w = 1 + (o - (h - 1) * 54); }
        else { int o2 = o - NIN;
            if (o2 < 56) { h = 0; w = o2; } else if (o2 < 112) { h = 55; w = o2 - 56; }
            else if (o2 < 166) { h = 1 + (o2 - 112); w = 0; } else { h = 1 + (o2 - 166); w = 55; } }
        const char* pb = xb + (size_t)(h * W + w) * 4;
        float acc = 0.0f;
        if (interior) {
            #pragma unroll 4
            for (int e = 0; e < nnz; ++e) { const int2 en = s_ent[e];
                acc = fmaf(__int_as_float(en.y), *(const float*)(pb + en.x), acc); }
        } else {
            const int h1 = h - 1, w1 = w - 1;
            for (int e = 0; e < nnz; ++e) { const int2 en = s_ent[e]; const int kk = s_kk[e];
                const int hh = h1 + (kk & 15), ww = w1 + (kk >> 4);
                if ((unsigned)hh < (unsigned)H && (unsigned)ww < (unsigned)W)
                    acc = fmaf(__int_as_float(en.y), *(const float*)(pb + en.x), acc); } }
        ob[h * W + w] = acc;
    }
}

// ---------------- launch ----------------

extern "C" void kernel_launch(void* const* d_in, const int* in_sizes, int n_in,
                              void* d_out, int out_size, void* d_ws, size_t ws_size,
                              hipStream_t stream) {
    const float* x = (const float*)d_in[0];
    const float* w = (const float*)d_in[1];
    float* out = (float*)d_out;

    if (ws_size >= WS_NEEDED) {
        ushort* xp = (ushort*)d_ws;
        ushort* wbp = xp + XP_ELEMS;
        prep_xp<<<BB * HP, 256, 0, stream>>>(x, xp);
        prep_wb2<<<(int)(WB_ELEMS / 256), 256, 0, stream>>>(w, wbp);
        conv_mfma<<<896, 256, 0, stream>>>(xp, wbp, out);
    } else {
        sparse_conv3x3<<<BB * COUT, 256, 0, stream>>>(x, w, out);
    }
}

// Round 16
// 143.727 us; speedup vs baseline: 1.3872x; 1.0478x over previous
//
#include <hip/hip_runtime.h>

// 3x3 conv (sparse weights treated dense), NCHW/OIHW, stride1 pad1, fp32 I/O.
// B=32, CIN=COUT=256, H=W=56.
//
// R16 = R15's 2-tap phase pipeline on m2n7 waves / 128-cout blocks ->
// 48KB LDS, (256,3) -> 3 blocks/CU = 3 waves/SIMD (1.5x R15's TLP).
//  - block 128 cout x 112 pix, 4 waves of 32c x 112p, acc[2][7] = 56 AGPR
//    (R9 measured 64 arch VGPR for this shape -> fits the ~170 (256,3) cap).
//  - A slab = 128 cout x 32 cin = 8KB; 2 parity bufs x 2 slabs = 32KB.
//    X single 16KB region buffer, split-staged (rows01 @ q2, rows23 @ q4).
//  - FIFO ledger re-walked for A2=4/A1=2/X=2 loads per thread:
//    head waits {q0:6, q1:4, q2:4, q3:4, q4:4}; never 0 mid-loop; cb7
//    wraps to dead targets; single drain at end. (Same calculus back-derives
//    R15's {10,8,8,6,8} -> method validated.)
//  - swizzle, phase order, epilogue mapping: R15 verbatim.

typedef __attribute__((ext_vector_type(8))) short short8;
typedef __attribute__((ext_vector_type(4))) float f32x4;
typedef __attribute__((ext_vector_type(4))) int i32x4;

constexpr int BB = 32, CIN = 256, COUT = 256, H = 56, W = 56, HW = H * W;
constexpr int HP = 58, WP = 58;

constexpr size_t XP_ELEMS = (size_t)BB * HP * WP * CIN;
constexpr size_t WB_ELEMS = (size_t)COUT * 9 * CIN;
constexpr size_t WS_NEEDED = (XP_ELEMS + WB_ELEMS) * 2;

__device__ __forceinline__ ushort f2bf(float f) {
    unsigned x = __float_as_uint(f);
    unsigned r = (x + 0x7FFFu + ((x >> 16) & 1u)) >> 16;   // RNE
    return (ushort)r;
}

// ---------------- prep kernels (unchanged) ----------------

__global__ __launch_bounds__(256)
void prep_xp(const float* __restrict__ x, ushort* __restrict__ xp) {
    const int bi = blockIdx.x;            // b*58 + padded row i
    const int b = bi / HP, i = bi % HP;
    ushort* dst = xp + (size_t)bi * WP * CIN;
    const int tid = threadIdx.x;

    if (i == 0 || i == HP - 1) {
        i32x4 z = {0, 0, 0, 0};
        for (int k = tid; k < WP * CIN / 8; k += 256) ((i32x4*)dst)[k] = z;
        return;
    }

    __shared__ ushort t[W][CIN + 2];
    const int lane = tid & 63, wv = tid >> 6;
    if (lane < W) {
        const float* src = x + (size_t)b * CIN * HW + (size_t)(i - 1) * W + lane;
        for (int cin = wv; cin < CIN; cin += 4)
            t[lane][cin] = f2bf(src[(size_t)cin * HW]);
    }
    __syncthreads();
    for (int c = 0; c < WP; ++c)
        dst[c * CIN + tid] = (c == 0 || c == WP - 1) ? (ushort)0 : t[c - 1][tid];
}

// wb2: [t = cb*9+tap][cout][ci], ci = cin%32. Slab = 8192 elems (256 couts).
__global__ __launch_bounds__(256)
void prep_wb2(const float* __restrict__ w, ushort* __restrict__ wb2) {
    const int d = blockIdx.x * 256 + threadIdx.x;
    const int ci = d & 31;
    const int cout = (d >> 5) & 255;
    const int r = d >> 13;                // 0..71
    const int tap = r % 9, cb = r / 9;
    const int cin = cb * 32 + ci;
    wb2[d] = f2bf(w[((size_t)cout * CIN + cin) * 9 + tap]);
}

// ---------------- MFMA conv ----------------

#define SCHED_FENCE() __builtin_amdgcn_sched_barrier(0)
#define WAITV(N) asm volatile("s_waitcnt vmcnt(" #N ")" ::: "memory")

__device__ __forceinline__ void gload_lds16(const ushort* g, ushort* l) {
    __builtin_amdgcn_global_load_lds(
        (const __attribute__((address_space(1))) void*)g,
        (__attribute__((address_space(3))) void*)l, 16, 0, 0);
}

// 16B-chunk involution: mixes bits 3-5 into 0-2; self-inverse; bits>=6 fixed.
__device__ __forceinline__ int swz(int c) { return c ^ ((c >> 3) & 7); }

__global__ __launch_bounds__(256, 3)
void conv_mfma(const ushort* __restrict__ xp, const ushort* __restrict__ wb2,
               float* __restrict__ out) {
    // XCD-aware swizzle: 1792 blocks = 8 * 224
    int bx = blockIdx.x;
    bx = (bx & 7) * 224 + (bx >> 3);

    const int mt = bx & 1;                 // cout tile: [128mt, 128mt+128)
    const int nt = bx >> 1;                // 896 = 32 b * 28 strips
    const int b  = nt / 28;
    const int p0 = (nt % 28) * 112;        // 112-pix strip = 2 output rows
    const int r0 = p0 / 56;                // first padded input row

    const int tid  = threadIdx.x;
    const int wv   = tid >> 6;             // 0..3, wave -> couts [32wv, 32wv+32) of tile
    const int lane = tid & 63;
    const int ml   = lane & 15;
    const int g    = lane >> 4;

    __shared__ ushort As0[2 * 4096], As1[2 * 4096];  // 2 bufs x 2 slabs(8KB) = 32KB
    __shared__ ushort Xs[4 * 2048];                  // 16KB: 4 row-regions x 256 chunks

    // A-frag read byte offsets within an 8KB slab (512 chunks), swizzled
    int aoffB[2];
    #pragma unroll
    for (int mi = 0; mi < 2; ++mi)
        aoffB[mi] = swz((32 * wv + 16 * mi + ml) * 4 + g) * 16;
    // B-frag chunk bases: pixel p_ = p0+16nf+ml -> region hl*256 + col*4 + g
    int cbase[7];
    #pragma unroll
    for (int nf = 0; nf < 7; ++nf) {
        const int p_  = p0 + 16 * nf + ml;
        const int hl  = (p_ >= p0 + 56) ? 1 : 0;
        const int col = p_ - 56 * (r0 + hl);
        cbase[nf] = hl * 256 + col * 4 + g;
    }
    // A staging source offsets (2 gloads/thread): position q = k*256+tid holds
    // chunk swz(q) of the 512-chunk half-slab.
    int goffA[2];
    #pragma unroll
    for (int k = 0; k < 2; ++k) {
        const int c = swz(k * 256 + tid);
        goffA[k] = (c >> 2) * 32 + (c & 3) * 8;                 // half-slab elems
    }
    // X row staging: position (rr*256+tid) holds chunk rr*256+ii (R13/R15 proven)
    int xoff;
    {
        const int ii = (tid & 0xC0) | ((tid & 63) ^ (((tid & 63) >> 3) & 7));
        xoff = (ii < 232) ? ((ii >> 2) * CIN + (ii & 3) * 8) : 0;
    }
    const size_t xbase = ((size_t)b * HP + r0) * WP * CIN;
    const ushort* wbase = wb2 + mt * 4096;   // this tile's cout-half of each slab

    f32x4 acc[2][7] = {};

    // stage a 2-slab A group starting at slab S (wraps at 72) into BUF
    #define STAGE_A2(S, BUF)                                                    \
        { _Pragma("unroll")                                                     \
          for (int s = 0; s < 2; ++s) {                                         \
              int _sl = (S) + s; if (_sl >= 72) _sl -= 72;                      \
              const ushort* _src = wbase + (size_t)_sl * 8192;                  \
              _Pragma("unroll")                                                 \
              for (int k = 0; k < 2; ++k)                                       \
                  gload_lds16(_src + goffA[k],                                  \
                              (BUF) + s * 4096 + (k * 256 + wv * 64) * 8);      \
          } }
    #define STAGE_A1(S, BUF)                                                    \
        { int _sl = (S); if (_sl >= 72) _sl -= 72;                              \
          const ushort* _src = wbase + (size_t)_sl * 8192;                      \
          _Pragma("unroll")                                                     \
          for (int k = 0; k < 2; ++k)                                           \
              gload_lds16(_src + goffA[k], (BUF) + (k * 256 + wv * 64) * 8); }
    #define STAGE_XPAIR(RR, CBN)                                                \
        { _Pragma("unroll")                                                     \
          for (int r_ = 0; r_ < 2; ++r_)                                        \
              gload_lds16(xp + xbase + (size_t)((RR) + r_) * WP * CIN           \
                              + (CBN) * 32 + xoff,                              \
                          &Xs[(((RR) + r_) * 256 + wv * 64) * 8]); }

    // prologue: X rows0-3(cb0), G(q0)->As0, G(q1)->As1; full drain; sync
    STAGE_XPAIR(0, 0);
    STAGE_XPAIR(2, 0);
    STAGE_A2(0, As0);
    STAGE_A2(2, As1);
    WAITV(0);
    __syncthreads();

    // phase q taps: q<4 -> {2q, 2q+1}; q4 -> {8}. buffer parity = (cb+q)&1.
    #define PHASE(CB, Q, NTAPS, HWAIT)                                          \
        {                                                                       \
            WAITV(HWAIT);                                                       \
            SCHED_FENCE();                                                      \
            __builtin_amdgcn_s_barrier();                                       \
            SCHED_FENCE();                                                      \
            const ushort* Ab = (((CB) + (Q)) & 1) ? As1 : As0;                  \
            _Pragma("unroll")                                                   \
            for (int tp = 0; tp < (NTAPS); ++tp) {                              \
                const int tap = 2 * (Q) + tp;                                   \
                const int kh = tap / 3, kw = tap - kh * 3;                      \
                short8 av[2], bv[7];                                            \
                _Pragma("unroll")                                               \
                for (int mi = 0; mi < 2; ++mi)                                  \
                    av[mi] = *(const short8*)((const char*)Ab + tp * 8192       \
                                              + aoffB[mi]);                     \
                _Pragma("unroll")                                               \
                for (int nf = 0; nf < 7; ++nf) {                                \
                    const int c = cbase[nf] + kh * 256 + kw * 4;                \
                    bv[nf] = *(const short8*)((const char*)Xs + swz(c) * 16);   \
                }                                                               \
                __builtin_amdgcn_s_setprio(1);                                  \
                _Pragma("unroll")                                               \
                for (int mi = 0; mi < 2; ++mi)                                  \
                    _Pragma("unroll")                                           \
                    for (int nf = 0; nf < 7; ++nf)                              \
                        acc[mi][nf] = __builtin_amdgcn_mfma_f32_16x16x32_bf16(  \
                                          av[mi], bv[nf], acc[mi][nf], 0, 0, 0);\
                __builtin_amdgcn_s_setprio(0);                                  \
            }                                                                   \
            SCHED_FENCE();                                                      \
            __builtin_amdgcn_s_barrier();                                       \
            SCHED_FENCE();                                                      \
        }

    for (int cbp = 0; cbp < 4; ++cbp) {
        #pragma unroll
        for (int hf = 0; hf < 2; ++hf) {
            const int cb  = 2 * cbp + hf;
            const int t0  = 9 * cb;
            const int cbn = (cb < 7) ? cb + 1 : 0;  // cb7: dummy (dead/drained)
            ushort* bufE = ((cb & 1) == 0) ? As0 : As1;  // parity (cb+q)&1 == 0
            ushort* bufO = ((cb & 1) == 0) ? As1 : As0;

            // q0: reads bufE; tail stages G(q2) into bufE
            PHASE(cb, 0, 2, 6);
            STAGE_A2(t0 + 4, bufE);
            SCHED_FENCE();
            // q1: reads bufO; tail stages G(q3) into bufO
            PHASE(cb, 1, 2, 4);
            STAGE_A2(t0 + 6, bufO);
            SCHED_FENCE();
            // q2: reads bufE; tail: X rows01(cb+1) FIRST, then G(q4) into bufE
            PHASE(cb, 2, 2, 4);
            STAGE_XPAIR(0, cbn);
            STAGE_A1(t0 + 8, bufE);
            SCHED_FENCE();
            // q3: reads bufO; tail stages G(next q0) into bufO
            PHASE(cb, 3, 2, 4);
            STAGE_A2(t0 + 9, bufO);
            SCHED_FENCE();
            // q4 (tap 8): reads bufE; tail: X rows23(cb+1), then G(next q1) into bufE
            PHASE(cb, 4, 1, 4);
            STAGE_XPAIR(2, cbn);
            STAGE_A2(t0 + 11, bufE);
            SCHED_FENCE();
        }
    }
    WAITV(0);                              // drain tail dummy stages

    // epilogue: D[row=4g+r][col=ml] (verified R2-R15)
    float* ob = out + (size_t)b * COUT * HW;
    #pragma unroll
    for (int mi = 0; mi < 2; ++mi)
        #pragma unroll
        for (int nf = 0; nf < 7; ++nf)
            #pragma unroll
            for (int r = 0; r < 4; ++r) {
                const int cout_l = mt * 128 + 32 * wv + 16 * mi + 4 * g + r;
                const int p_ = p0 + 16 * nf + ml;
                ob[(size_t)cout_l * HW + p_] = acc[mi][nf][r];
            }
    #undef STAGE_A2
    #undef STAGE_A1
    #undef STAGE_XPAIR
    #undef PHASE
}

// ---------------- R1 fallback (fp32 sparse direct) ----------------

constexpr int WSZ = CIN * 9;
constexpr int NIN = 54 * 54;

__global__ __launch_bounds__(256)
void sparse_conv3x3(const float* __restrict__ x,
                    const float* __restrict__ wgt,
                    float* __restrict__ out) {
    const int bc = blockIdx.x, cout = bc % COUT, b = bc / COUT;
    const int tid = threadIdx.x;
    __shared__ int2 s_ent[WSZ];
    __shared__ unsigned char s_kk[WSZ];
    __shared__ int s_cnt[257];
    const float* wc = wgt + (size_t)cout * WSZ;
    float mv[9]; int cnt = 0;
    #pragma unroll
    for (int i = 0; i < 9; ++i) { mv[i] = wc[tid * 9 + i]; if (mv[i] != 0.0f) cnt++; }
    s_cnt[tid] = cnt; __syncthreads();
    if (tid == 0) { int run = 0; for (int t = 0; t < 256; ++t) { int c = s_cnt[t]; s_cnt[t] = run; run += c; } s_cnt[256] = run; }
    __syncthreads();
    { int pos = s_cnt[tid];
      #pragma unroll
      for (int i = 0; i < 9; ++i) if (mv[i] != 0.0f) {
          const int kh = i / 3, kw = i - kh * 3;
          int2 e; e.x = (tid * HW + (kh - 1) * W + (kw - 1)) * 4; e.y = __float_as_int(mv[i]);
          s_ent[pos] = e; s_kk[pos] = (unsigned char)(kh | (kw << 4)); pos++; } }
    __syncthreads();
    const int nnz = s_cnt[256];
    const char* xb = (const char*)(x + (size_t)b * CIN * HW);
    float* ob = out + (size_t)bc * HW;
    for (int o = tid; o < HW; o += 256) {
        int h, w; bool interior = (o < NIN);
        if (interior) { h = 1 + o / 54; w = 1 + (o - (h - 1) * 54); }
        else { int o2 = o - NIN;
            if (o2 < 56) { h = 0; w = o2; } else if (o2 < 112) { h = 55; w = o2 - 56; }
            else if (o2 < 166) { h = 1 + (o2 - 112); w = 0; } else { h = 1 + (o2 - 166); w = 55; } }
        const char* pb = xb + (size_t)(h * W + w) * 4;
        float acc = 0.0f;
        if (interior) {
            #pragma unroll 4
            for (int e = 0; e < nnz; ++e) { const int2 en = s_ent[e];
                acc = fmaf(__int_as_float(en.y), *(const float*)(pb + en.x), acc); }
        } else {
            const int h1 = h - 1, w1 = w - 1;
            for (int e = 0; e < nnz; ++e) { const int2 en = s_ent[e]; const int kk = s_kk[e];
                const int hh = h1 + (kk & 15), ww = w1 + (kk >> 4);
                if ((unsigned)hh < (unsigned)H && (unsigned)ww < (unsigned)W)
                    acc = fmaf(__int_as_float(en.y), *(const float*)(pb + en.x), acc); } }
        ob[h * W + w] = acc;
    }
}

// ---------------- launch ----------------

extern "C" void kernel_launch(void* const* d_in, const int* in_sizes, int n_in,
                              void* d_out, int out_size, void* d_ws, size_t ws_size,
                              hipStream_t stream) {
    const float* x = (const float*)d_in[0];
    const float* w = (const float*)d_in[1];
    float* out = (float*)d_out;

    if (ws_size >= WS_NEEDED) {
        ushort* xp = (ushort*)d_ws;
        ushort* wbp = xp + XP_ELEMS;
        prep_xp<<<BB * HP, 256, 0, stream>>>(x, xp);
        prep_wb2<<<(int)(WB_ELEMS / 256), 256, 0, stream>>>(w, wbp);
        conv_mfma<<<1792, 256, 0, stream>>>(xp, wbp, out);
    } else {
        sparse_conv3x3<<<BB * COUT, 256, 0, stream>>>(x, w, out);
    }
}